// Round 4
// baseline (223.149 us; speedup 1.0000x reference)
//
#include <hip/hip_runtime.h>
#include <hip/hip_bf16.h>
#include <math.h>

// Problem constants
#define B_    16
#define C_    256
#define L_    64
#define N_    8192
#define HEAD_ 8
#define HC_   32        // C/HEAD
#define M_    12

#define SQRT32F 5.656854249492380f
#define PI_F    3.14159265358979323846f
#define BN_INV  0.99999500003749969f     // 1/sqrt(1+1e-5)

// ---------------------------------------------------------------------------
// Encoder: one block per (b,h). Naive and transparent. f32 in / f32 out.
// ---------------------------------------------------------------------------
__global__ __launch_bounds__(256) void encoder_kernel(
    const float* __restrict__ xt, const float* __restrict__ enc_w,
    const float* __restrict__ enc_b, const float* __restrict__ weights,
    float* __restrict__ enc)
{
    __shared__ float qkv_s[3][HC_][L_];   // 24 KB
    __shared__ float P[L_][L_];           // 16 KB
    const int t = threadIdx.x;
    const int b = blockIdx.x >> 3;
    const int h = blockIdx.x & 7;
    const float* xtb = xt + (size_t)b * (C_ * L_);

    // phase 1: qkv_s[sec][cc][l] = enc_b[o] + sum_c enc_w[o,c] * xt[b,c,l]
    for (int idx = t; idx < 3 * HC_ * L_; idx += 256) {
        int sec = idx / (HC_ * L_);
        int rem = idx % (HC_ * L_);
        int cc  = rem / L_;
        int l   = rem % L_;
        int o   = sec * C_ + h * HC_ + cc;
        const float* wrow = enc_w + (size_t)o * C_;
        float s = enc_b[o];
        for (int c = 0; c < C_; ++c) s += wrow[c] * xtb[c * L_ + l];
        qkv_s[sec][cc][l] = s;
    }
    __syncthreads();

    // phase 2: logits P[l][lp] = sqrt(32) * sum_cc q[cc][l] * k[cc][lp]
    for (int idx = t; idx < L_ * L_; idx += 256) {
        int l = idx / L_, lp = idx % L_;
        float s = 0.f;
        for (int cc = 0; cc < HC_; ++cc) s += qkv_s[0][cc][l] * qkv_s[1][cc][lp];
        P[l][lp] = s * SQRT32F;
    }
    __syncthreads();

    // phase 3: softmax along lp, one thread per row, fully serial
    if (t < L_) {
        float m = -1e30f;
        for (int j = 0; j < L_; ++j) m = fmaxf(m, P[t][j]);
        float sum = 0.f;
        for (int j = 0; j < L_; ++j) { float e = expf(P[t][j] - m); P[t][j] = e; sum += e; }
        float inv = 1.0f / sum;
        for (int j = 0; j < L_; ++j) P[t][j] *= inv;
    }
    __syncthreads();

    // phase 4: a[l,cc] = sum_s P[l][s] * v[cc][s]; enc = fourier(a) + xt
    for (int idx = t; idx < L_ * HC_; idx += 256) {
        int l = idx / HC_, cc = idx % HC_;
        float a = 0.f;
        for (int s = 0; s < L_; ++s) a += P[l][s] * qkv_s[2][cc][s];
        int c = h * HC_ + cc;
        float val = xtb[c * L_ + l];
        const float* wr = weights + c * (2 * M_);
        for (int m = 0; m < M_; ++m) {
            float ph = ((float)m / (float)M_) * a * PI_F;
            val += wr[m] * sinf(ph) + wr[M_ + m] * cosf(ph);
        }
        enc[((size_t)b * C_ + c) * L_ + l] = val;
    }
}

// ---------------------------------------------------------------------------
// Decoder + fc1 + fc2: one block per batch. Query constant over (b,n).
// ---------------------------------------------------------------------------
__global__ __launch_bounds__(256) void decoder_kernel(
    const float* __restrict__ enc, const float* __restrict__ mt,
    const float* __restrict__ dec_w, const float* __restrict__ dec_b,
    const float* __restrict__ fc1_w, const float* __restrict__ fc1_g,
    const float* __restrict__ fc1_b, const float* __restrict__ fc2_w,
    const float* __restrict__ fc2_g, const float* __restrict__ fc2_b,
    float* __restrict__ xnp_out, float* __restrict__ y2_out)
{
    __shared__ float mts[C_];
    __shared__ float qv[C_];
    __shared__ float sc[L_];
    __shared__ float xnp[C_];
    __shared__ float y1[C_];
    const int t = threadIdx.x;
    const int b = blockIdx.x;
    const float* encb = enc + (size_t)b * C_ * L_;

    mts[t] = mt[t];
    __syncthreads();

    // qv[o] = dec_b[o] + sum_c dec_w[o,c] * mask_token[c]
    {
        const float* wrow = dec_w + (size_t)t * C_;
        float s = dec_b[t];
        for (int c = 0; c < C_; ++c) s += wrow[c] * mts[c];
        qv[t] = s;
    }
    __syncthreads();

    for (int h = 0; h < HEAD_; ++h) {
        if (t < L_) {
            float s = 0.f;
            for (int cc = 0; cc < HC_; ++cc)
                s += qv[h * HC_ + cc] * encb[(h * HC_ + cc) * L_ + t];
            sc[t] = s * SQRT32F;
        }
        __syncthreads();
        if (t == 0) {
            float m = -1e30f;
            for (int j = 0; j < L_; ++j) m = fmaxf(m, sc[j]);
            float sum = 0.f;
            for (int j = 0; j < L_; ++j) { float e = expf(sc[j] - m); sc[j] = e; sum += e; }
            float inv = 1.0f / sum;
            for (int j = 0; j < L_; ++j) sc[j] *= inv;
        }
        __syncthreads();
        if (t < HC_) {
            float s = 0.f;
            for (int k = 0; k < L_; ++k) s += sc[k] * encb[(h * HC_ + t) * L_ + k];
            xnp[h * HC_ + t] = s + mts[h * HC_ + t];
        }
        __syncthreads();
    }

    xnp_out[b * C_ + t] = xnp[t];

    // fc1 + BN(eval) + LeakyReLU(0.2)
    {
        const float* wrow = fc1_w + (size_t)t * C_;
        float s = 0.f;
        for (int c = 0; c < C_; ++c) s += wrow[c] * xnp[c];
        float y = fc1_g[t] * s * BN_INV + fc1_b[t];
        y1[t] = (y >= 0.f) ? y : 0.2f * y;
    }
    __syncthreads();

    if (t < 3) {
        float s = 0.f;
        for (int c = 0; c < C_; ++c) s += fc2_w[t * C_ + c] * y1[c];
        float y = fc2_g[t] * s * BN_INV + fc2_b[t];
        y2_out[b * 3 + t] = (y >= 0.f) ? y : 0.2f * y;
    }
}

// ---------------------------------------------------------------------------
// Broadcast outputs (FLOAT32 — reference output dtype).
//   out0[b,c,n] = xnp[b,c]   (blocks 0..4095, one per (b,c))
//   out1[b,n,j] = y2[b,j]    (blocks 4096..4111, one per b)
// ---------------------------------------------------------------------------
__global__ __launch_bounds__(256) void bcast_out(const float* __restrict__ xnp,
                                                 const float* __restrict__ y2,
                                                 float* __restrict__ out) {
    const int t = threadIdx.x;
    const int blk = blockIdx.x;
    if (blk < 4096) {
        float v = xnp[blk];
        float4 V = make_float4(v, v, v, v);
        float4* row = reinterpret_cast<float4*>(out + (size_t)blk * N_);
        #pragma unroll
        for (int i = 0; i < 8; ++i) row[t + i * 256] = V;   // 2048 x 16B = 8192 f32
    } else {
        int b = blk - 4096;
        float* o1 = out + (size_t)B_ * C_ * N_ + (size_t)b * (N_ * 3);
        float v0 = y2[b * 3 + 0];
        float v1 = y2[b * 3 + 1];
        float v2 = y2[b * 3 + 2];
        for (int idx = t; idx < N_ * 3; idx += 256) {
            int j = idx % 3;
            o1[idx] = (j == 0) ? v0 : ((j == 1) ? v1 : v2);
        }
    }
}

// ---------------------------------------------------------------------------
extern "C" void kernel_launch(void* const* d_in, const int* in_sizes, int n_in,
                              void* d_out, int out_size, void* d_ws, size_t ws_size,
                              hipStream_t stream) {
    const float* xt      = (const float*)d_in[0];
    // d_in[1] = xn : unused (only its length N matters; compile-time here)
    const float* weights = (const float*)d_in[2];
    const float* mt      = (const float*)d_in[3];
    const float* enc_w   = (const float*)d_in[4];
    const float* enc_b   = (const float*)d_in[5];
    const float* dec_w   = (const float*)d_in[6];
    const float* dec_b   = (const float*)d_in[7];
    const float* fc1_w   = (const float*)d_in[8];
    const float* fc1_g   = (const float*)d_in[9];
    const float* fc1_b   = (const float*)d_in[10];
    const float* fc2_w   = (const float*)d_in[11];
    const float* fc2_g   = (const float*)d_in[12];
    const float* fc2_b   = (const float*)d_in[13];

    float* ws  = (float*)d_ws;
    float* enc = ws;                  // 16*256*64 = 262144 floats (1 MB)
    float* xnp = ws + 262144;         // 4096 floats
    float* y2  = ws + 266240;         // 48 floats

    float* out = (float*)d_out;

    encoder_kernel<<<128, 256, 0, stream>>>(xt, enc_w, enc_b, weights, enc);
    decoder_kernel<<<16, 256, 0, stream>>>(enc, mt, dec_w, dec_b,
                                           fc1_w, fc1_g, fc1_b,
                                           fc2_w, fc2_g, fc2_b, xnp, y2);
    bcast_out<<<4112, 256, 0, stream>>>(xnp, y2, out);
}

// Round 5
// 94.710 us; speedup vs baseline: 2.3561x; 2.3561x over previous
//
#include <hip/hip_runtime.h>
#include <hip/hip_bf16.h>
#include <math.h>

// Problem constants
#define B_    16
#define C_    256
#define L_    64
#define N_    8192
#define HEAD_ 8
#define HC_   32        // C/HEAD
#define M_    12
#define BL_   1024      // B*L

#define SQRT32F 5.656854249492380f
#define PI_F    3.14159265358979323846f
#define BN_INV  0.99999500003749969f     // 1/sqrt(1+1e-5)

// ---------------------------------------------------------------------------
// Kernel A: qkv = enc_w (768x256) @ X (256x1024) + enc_b  (tiled LDS GEMM)
// X[c, b*64+l] = xt[b,c,l].  Y[o][b*64+l], row stride 1024.
// ---------------------------------------------------------------------------
__global__ __launch_bounds__(256) void qkv_gemm(const float* __restrict__ enc_w,
                                                const float* __restrict__ enc_b,
                                                const float* __restrict__ xt,
                                                float* __restrict__ Y) {
    __shared__ float As[64][33];
    __shared__ float Bs[32][64];
    const int t  = threadIdx.x;
    const int b  = blockIdx.x;        // 0..15
    const int o0 = blockIdx.y * 64;   // 0..11 tiles
    const float* xb = xt + (size_t)b * (C_ * L_);
    const int tx = t & 15, ty = t >> 4;
    float acc[4][4] = {};

    for (int k0 = 0; k0 < 256; k0 += 32) {
        #pragma unroll
        for (int i = 0; i < 8; ++i) {
            int idx = t + i * 256;            // 0..2047
            int r = idx >> 5, kk = idx & 31;
            As[r][kk] = enc_w[(size_t)(o0 + r) * 256 + k0 + kk];
        }
        #pragma unroll
        for (int i = 0; i < 8; ++i) {
            int idx = t + i * 256;            // 0..2047
            int kk = idx >> 6, jj = idx & 63;
            Bs[kk][jj] = xb[(k0 + kk) * 64 + jj];
        }
        __syncthreads();
        #pragma unroll
        for (int kk = 0; kk < 32; ++kk) {
            float a[4], bv[4];
            #pragma unroll
            for (int i = 0; i < 4; ++i) a[i] = As[ty * 4 + i][kk];
            #pragma unroll
            for (int j = 0; j < 4; ++j) bv[j] = Bs[kk][tx * 4 + j];
            #pragma unroll
            for (int i = 0; i < 4; ++i)
                #pragma unroll
                for (int j = 0; j < 4; ++j)
                    acc[i][j] += a[i] * bv[j];
        }
        __syncthreads();
    }
    #pragma unroll
    for (int i = 0; i < 4; ++i) {
        int o = o0 + ty * 4 + i;
        float bias = enc_b[o];
        #pragma unroll
        for (int j = 0; j < 4; ++j)
            Y[(size_t)o * BL_ + b * 64 + tx * 4 + j] = acc[i][j] + bias;
    }
}

// ---------------------------------------------------------------------------
// Kernel B: per (b,h) attention + Fourier + residual. Reads qkv from Y.
// LDS padded to kill bank conflicts (stride 65 ≡ 1 mod 32 banks).
// ---------------------------------------------------------------------------
__global__ __launch_bounds__(256) void enc_attn(const float* __restrict__ Y,
                                                const float* __restrict__ xt,
                                                const float* __restrict__ weights,
                                                float* __restrict__ enc) {
    __shared__ float qs[HC_][L_];      // read wave-uniform row, lane-consec col
    __shared__ float ks[HC_][L_];
    __shared__ float vs[HC_][L_ + 1];  // read column-wise along s: padded
    __shared__ float P[L_][L_ + 1];    // padded
    const int t = threadIdx.x;
    const int b = blockIdx.x >> 3;
    const int h = blockIdx.x & 7;
    const float* xtb = xt + (size_t)b * (C_ * L_);

    // load q,k,v slices (coalesced over l)
    for (int idx = t; idx < HC_ * L_; idx += 256) {
        int cc = idx >> 6, l = idx & 63;
        int col = b * 64 + l;
        qs[cc][l] = Y[(size_t)(      h * HC_ + cc) * BL_ + col];
        ks[cc][l] = Y[(size_t)(256 + h * HC_ + cc) * BL_ + col];
        vs[cc][l] = Y[(size_t)(512 + h * HC_ + cc) * BL_ + col];
    }
    __syncthreads();

    // scores P[l][lp] = sqrt(32) * sum_cc q[cc][l] * k[cc][lp]
    for (int idx = t; idx < L_ * L_; idx += 256) {
        int l = idx >> 6, lp = idx & 63;
        float s = 0.f;
        #pragma unroll
        for (int cc = 0; cc < HC_; ++cc) s += qs[cc][l] * ks[cc][lp];
        P[l][lp] = s * SQRT32F;
    }
    __syncthreads();

    // softmax along lp, one thread per row (padded P -> 2-way max, free)
    if (t < L_) {
        float m = -1e30f;
        #pragma unroll
        for (int j = 0; j < L_; ++j) m = fmaxf(m, P[t][j]);
        float sum = 0.f;
        #pragma unroll
        for (int j = 0; j < L_; ++j) { float e = __expf(P[t][j] - m); P[t][j] = e; sum += e; }
        float inv = 1.0f / sum;
        #pragma unroll
        for (int j = 0; j < L_; ++j) P[t][j] *= inv;
    }
    __syncthreads();

    // PV + Fourier + residual; l fastest -> coalesced enc writes
    for (int idx = t; idx < L_ * HC_; idx += 256) {
        int cc = idx >> 6, l = idx & 63;
        float a = 0.f;
        #pragma unroll
        for (int s = 0; s < L_; ++s) a += P[l][s] * vs[cc][s];
        int c = h * HC_ + cc;
        float val = xtb[c * L_ + l];
        const float* wr = weights + c * (2 * M_);
        float base = a * (PI_F / (float)M_);
        #pragma unroll
        for (int m = 0; m < M_; ++m) {
            float sn, cs;
            __sincosf((float)m * base, &sn, &cs);
            val += wr[m] * sn + wr[M_ + m] * cs;
        }
        enc[((size_t)b * C_ + c) * L_ + l] = val;
    }
}

// ---------------------------------------------------------------------------
// Decoder + fc1 + fc2: one block per batch. Query constant over (b,n).
// ---------------------------------------------------------------------------
__global__ __launch_bounds__(256) void decoder_kernel(
    const float* __restrict__ enc, const float* __restrict__ mt,
    const float* __restrict__ dec_w, const float* __restrict__ dec_b,
    const float* __restrict__ fc1_w, const float* __restrict__ fc1_g,
    const float* __restrict__ fc1_b, const float* __restrict__ fc2_w,
    const float* __restrict__ fc2_g, const float* __restrict__ fc2_b,
    float* __restrict__ xnp_out, float* __restrict__ y2_out)
{
    __shared__ float mts[C_];
    __shared__ float qv[C_];
    __shared__ float aw[L_];
    __shared__ float xnp[C_];
    __shared__ float y1[C_];
    const int t = threadIdx.x;
    const int b = blockIdx.x;
    const float* encb = enc + (size_t)b * C_ * L_;

    mts[t] = mt[t];
    __syncthreads();

    // qv[o] = dec_b[o] + sum_c dec_w[o,c] * mask_token[c]
    {
        const float* wrow = dec_w + (size_t)t * C_;
        float s = dec_b[t];
        #pragma unroll 8
        for (int c = 0; c < C_; ++c) s += wrow[c] * mts[c];
        qv[t] = s;
    }
    __syncthreads();

    for (int h = 0; h < HEAD_; ++h) {
        if (t < L_) {   // full wave 0 -> shuffle-safe
            float s = 0.f;
            #pragma unroll
            for (int cc = 0; cc < HC_; ++cc)
                s += qv[h * HC_ + cc] * encb[(h * HC_ + cc) * L_ + t];
            s *= SQRT32F;
            float m = s;
            #pragma unroll
            for (int off = 32; off >= 1; off >>= 1) m = fmaxf(m, __shfl_xor(m, off));
            float e = __expf(s - m);
            float sum = e;
            #pragma unroll
            for (int off = 32; off >= 1; off >>= 1) sum += __shfl_xor(sum, off);
            aw[t] = e / sum;
        }
        __syncthreads();
        if (t < HC_) {
            float s = 0.f;
            #pragma unroll
            for (int k = 0; k < L_; ++k) s += aw[k] * encb[(h * HC_ + t) * L_ + k];
            xnp[h * HC_ + t] = s + mts[h * HC_ + t];
        }
        __syncthreads();
    }

    xnp_out[b * C_ + t] = xnp[t];

    // fc1 + BN(eval) + LeakyReLU(0.2)
    {
        const float* wrow = fc1_w + (size_t)t * C_;
        float s = 0.f;
        #pragma unroll 8
        for (int c = 0; c < C_; ++c) s += wrow[c] * xnp[c];
        float y = fc1_g[t] * s * BN_INV + fc1_b[t];
        y1[t] = (y >= 0.f) ? y : 0.2f * y;
    }
    __syncthreads();

    if (t < 3) {
        float s = 0.f;
        for (int c = 0; c < C_; ++c) s += fc2_w[t * C_ + c] * y1[c];
        float y = fc2_g[t] * s * BN_INV + fc2_b[t];
        y2_out[b * 3 + t] = (y >= 0.f) ? y : 0.2f * y;
    }
}

// ---------------------------------------------------------------------------
// Broadcast outputs (f32).
//   out0[b,c,n] = xnp[b,c]   (blocks 0..4095, one per (b,c))
//   out1[b,n,j] = y2[b,j]    (blocks 4096..4111, one per b)
// ---------------------------------------------------------------------------
__global__ __launch_bounds__(256) void bcast_out(const float* __restrict__ xnp,
                                                 const float* __restrict__ y2,
                                                 float* __restrict__ out) {
    const int t = threadIdx.x;
    const int blk = blockIdx.x;
    if (blk < 4096) {
        float v = xnp[blk];
        float4 V = make_float4(v, v, v, v);
        float4* row = reinterpret_cast<float4*>(out + (size_t)blk * N_);
        #pragma unroll
        for (int i = 0; i < 8; ++i) row[t + i * 256] = V;   // 2048 x 16B = 8192 f32
    } else {
        int b = blk - 4096;
        float* o1 = out + (size_t)B_ * C_ * N_ + (size_t)b * (N_ * 3);
        float v0 = y2[b * 3 + 0];
        float v1 = y2[b * 3 + 1];
        float v2 = y2[b * 3 + 2];
        for (int idx = t; idx < N_ * 3; idx += 256) {
            int j = idx % 3;
            o1[idx] = (j == 0) ? v0 : ((j == 1) ? v1 : v2);
        }
    }
}

// ---------------------------------------------------------------------------
extern "C" void kernel_launch(void* const* d_in, const int* in_sizes, int n_in,
                              void* d_out, int out_size, void* d_ws, size_t ws_size,
                              hipStream_t stream) {
    const float* xt      = (const float*)d_in[0];
    // d_in[1] = xn : unused (only its length N matters; compile-time here)
    const float* weights = (const float*)d_in[2];
    const float* mt      = (const float*)d_in[3];
    const float* enc_w   = (const float*)d_in[4];
    const float* enc_b   = (const float*)d_in[5];
    const float* dec_w   = (const float*)d_in[6];
    const float* dec_b   = (const float*)d_in[7];
    const float* fc1_w   = (const float*)d_in[8];
    const float* fc1_g   = (const float*)d_in[9];
    const float* fc1_b   = (const float*)d_in[10];
    const float* fc2_w   = (const float*)d_in[11];
    const float* fc2_g   = (const float*)d_in[12];
    const float* fc2_b   = (const float*)d_in[13];

    float* ws  = (float*)d_ws;
    float* Y   = ws;                  // 768*1024 = 786432 floats (3 MB)
    float* enc = ws + 786432;         // 262144 floats (1 MB)
    float* xnp = ws + 1048576;        // 4096 floats
    float* y2  = ws + 1052672;        // 48 floats

    float* out = (float*)d_out;

    qkv_gemm<<<dim3(16, 12), 256, 0, stream>>>(enc_w, enc_b, xt, Y);
    enc_attn<<<128, 256, 0, stream>>>(Y, xt, weights, enc);
    decoder_kernel<<<16, 256, 0, stream>>>(enc, mt, dec_w, dec_b,
                                           fc1_w, fc1_g, fc1_b,
                                           fc2_w, fc2_g, fc2_b, xnp, y2);
    bcast_out<<<4112, 256, 0, stream>>>(xnp, y2, out);
}

// Round 6
// 83.231 us; speedup vs baseline: 2.6811x; 1.1379x over previous
//
#include <hip/hip_runtime.h>
#include <hip/hip_bf16.h>
#include <math.h>

// Problem constants
#define B_    16
#define C_    256
#define L_    64
#define N_    8192
#define HEAD_ 8
#define HC_   32        // C/HEAD
#define M_    12
#define BL_   1024      // B*L

#define SQRT32F 5.656854249492380f
#define PI_F    3.14159265358979323846f
#define BN_INV  0.99999500003749969f     // 1/sqrt(1+1e-5)

// ---------------------------------------------------------------------------
// Kernel A: qkv = enc_w (768x256) @ X (256x1024) + enc_b
// Tile 64x64, 128 threads, 4x8 register tile, float4 LDS reads both sides.
// Thread cols: {tx*4..tx*4+3} and {32+tx*4..}; rows: ty*4..ty*4+3.
// ---------------------------------------------------------------------------
__global__ __launch_bounds__(128) void qkv_gemm(const float* __restrict__ enc_w,
                                                const float* __restrict__ enc_b,
                                                const float* __restrict__ xt,
                                                float* __restrict__ Y) {
    __shared__ float As_t[32][68];   // [kk][r] transposed, padded for b128
    __shared__ float Bs[32][64];
    const int t  = threadIdx.x;          // 0..127
    const int b  = blockIdx.x;           // 0..15
    const int o0 = blockIdx.y * 64;      // 0..11 tiles
    const float* xb = xt + (size_t)b * (C_ * L_);
    const int tx = t & 7;                // N: 8 groups
    const int ty = t >> 3;               // M: 16 groups
    float4 accA[4] = {};                 // cols tx*4+j
    float4 accB[4] = {};                 // cols 32+tx*4+j

    for (int k0 = 0; k0 < 256; k0 += 32) {
        // A tile: 64 rows x 32 k, load float4 along k, store transposed
        #pragma unroll
        for (int i = 0; i < 4; ++i) {
            int q = t + i * 128;             // 0..511 quads
            int kk4 = (q & 7) * 4, r = q >> 3;
            float4 w4 = *reinterpret_cast<const float4*>(
                &enc_w[(size_t)(o0 + r) * 256 + k0 + kk4]);
            As_t[kk4 + 0][r] = w4.x;
            As_t[kk4 + 1][r] = w4.y;
            As_t[kk4 + 2][r] = w4.z;
            As_t[kk4 + 3][r] = w4.w;
        }
        // B tile: 32 k x 64 cols, float4
        #pragma unroll
        for (int i = 0; i < 4; ++i) {
            int q = t + i * 128;             // 0..511 quads
            int jj4 = (q & 15) * 4, kk = q >> 4;
            *reinterpret_cast<float4*>(&Bs[kk][jj4]) =
                *reinterpret_cast<const float4*>(&xb[(k0 + kk) * 64 + jj4]);
        }
        __syncthreads();
        #pragma unroll
        for (int kk = 0; kk < 32; ++kk) {
            float4 a4 = *reinterpret_cast<const float4*>(&As_t[kk][ty * 4]);
            float4 bA = *reinterpret_cast<const float4*>(&Bs[kk][tx * 4]);
            float4 bB = *reinterpret_cast<const float4*>(&Bs[kk][32 + tx * 4]);
            float as[4] = {a4.x, a4.y, a4.z, a4.w};
            #pragma unroll
            for (int ii = 0; ii < 4; ++ii) {
                accA[ii].x += as[ii] * bA.x; accA[ii].y += as[ii] * bA.y;
                accA[ii].z += as[ii] * bA.z; accA[ii].w += as[ii] * bA.w;
                accB[ii].x += as[ii] * bB.x; accB[ii].y += as[ii] * bB.y;
                accB[ii].z += as[ii] * bB.z; accB[ii].w += as[ii] * bB.w;
            }
        }
        __syncthreads();
    }
    #pragma unroll
    for (int ii = 0; ii < 4; ++ii) {
        int o = o0 + ty * 4 + ii;
        float bias = enc_b[o];
        float4 wA = accA[ii]; wA.x += bias; wA.y += bias; wA.z += bias; wA.w += bias;
        float4 wB = accB[ii]; wB.x += bias; wB.y += bias; wB.z += bias; wB.w += bias;
        float* row = Y + (size_t)o * BL_ + b * 64;
        *reinterpret_cast<float4*>(&row[tx * 4])      = wA;
        *reinterpret_cast<float4*>(&row[32 + tx * 4]) = wB;
    }
}

// ---------------------------------------------------------------------------
// Kernel B: per (b,h,half) attention + Fourier + residual.
// 256 blocks (full CU coverage); each handles 32 query rows.
// ---------------------------------------------------------------------------
__global__ __launch_bounds__(256) void enc_attn(const float* __restrict__ Y,
                                                const float* __restrict__ xt,
                                                const float* __restrict__ weights,
                                                float* __restrict__ enc) {
    __shared__ float qs[HC_][33];        // [cc][l_local], scalar-read only
    __shared__ float ks[HC_][68];        // padded for aligned float4
    __shared__ float vs[HC_][68];
    __shared__ float P[32][68];          // 32 query rows x 64 keys
    const int t    = threadIdx.x;
    const int bh   = blockIdx.x >> 1;
    const int half = blockIdx.x & 1;
    const int b    = bh >> 3;
    const int h    = bh & 7;
    const float* xtb = xt + (size_t)b * (C_ * L_);

    // stage k, v (full 64 keys) and q (this half's 32 rows)
    for (int idx = t; idx < HC_ * L_; idx += 256) {
        int cc = idx >> 6, l = idx & 63;
        int col = b * 64 + l;
        ks[cc][l] = Y[(size_t)(256 + h * HC_ + cc) * BL_ + col];
        vs[cc][l] = Y[(size_t)(512 + h * HC_ + cc) * BL_ + col];
    }
    for (int idx = t; idx < HC_ * 32; idx += 256) {
        int cc = idx >> 5, l = idx & 31;
        qs[cc][l] = Y[(size_t)(h * HC_ + cc) * BL_ + b * 64 + half * 32 + l];
    }
    __syncthreads();

    // scores: P[l][lp] = sqrt(32) * sum_cc q[cc][l] * k[cc][lp], quad over lp
    #pragma unroll
    for (int i = 0; i < 2; ++i) {
        int e4 = t + i * 256;            // 0..511 quad-slots
        int l  = e4 >> 4;                // 0..31
        int lq = (e4 & 15) * 4;          // lp quad start
        float4 a4 = make_float4(0.f, 0.f, 0.f, 0.f);
        #pragma unroll
        for (int cc = 0; cc < HC_; ++cc) {
            float4 k4 = *reinterpret_cast<const float4*>(&ks[cc][lq]);
            float qv_ = qs[cc][l];
            a4.x += qv_ * k4.x; a4.y += qv_ * k4.y;
            a4.z += qv_ * k4.z; a4.w += qv_ * k4.w;
        }
        a4.x *= SQRT32F; a4.y *= SQRT32F; a4.z *= SQRT32F; a4.w *= SQRT32F;
        *reinterpret_cast<float4*>(&P[l][lq]) = a4;
    }
    __syncthreads();

    // softmax per row: 4 threads/row x 16 cols, shfl-xor combine (waves 0,1)
    if (t < 128) {
        int l = t >> 2, p0 = (t & 3) * 16;
        float m = -1e30f;
        #pragma unroll
        for (int j = 0; j < 16; ++j) m = fmaxf(m, P[l][p0 + j]);
        m = fmaxf(m, __shfl_xor(m, 1));
        m = fmaxf(m, __shfl_xor(m, 2));
        float sum = 0.f;
        #pragma unroll
        for (int j = 0; j < 16; ++j) {
            float e = __expf(P[l][p0 + j] - m);
            P[l][p0 + j] = e;
            sum += e;
        }
        sum += __shfl_xor(sum, 1);
        sum += __shfl_xor(sum, 2);
        float inv = 1.0f / sum;
        #pragma unroll
        for (int j = 0; j < 16; ++j) P[l][p0 + j] *= inv;
    }
    __syncthreads();

    // PV + Fourier + residual; lanes consecutive in l -> coalesced writes
    #pragma unroll
    for (int i = 0; i < 4; ++i) {
        int e  = t + i * 256;            // 0..1023
        int l  = e & 31;                 // local query row
        int cc = e >> 5;                 // 0..31
        float a = 0.f;
        #pragma unroll
        for (int sq = 0; sq < 16; ++sq) {
            float4 p4 = *reinterpret_cast<const float4*>(&P[l][sq * 4]);
            float4 v4 = *reinterpret_cast<const float4*>(&vs[cc][sq * 4]);
            a += p4.x * v4.x + p4.y * v4.y + p4.z * v4.z + p4.w * v4.w;
        }
        int c  = h * HC_ + cc;
        int lg = half * 32 + l;
        float val = xtb[c * L_ + lg];
        const float* wr = weights + c * (2 * M_);
        float base = a * (PI_F / (float)M_);
        #pragma unroll
        for (int m = 0; m < M_; ++m) {
            float sn, cs;
            __sincosf((float)m * base, &sn, &cs);
            val += wr[m] * sn + wr[M_ + m] * cs;
        }
        enc[((size_t)b * C_ + c) * L_ + lg] = val;
    }
}

// ---------------------------------------------------------------------------
// Kernel C: decoder + fc1 + fc2, one block per batch, 512 threads.
// All 8 heads in parallel: wave w == head w (t = h*64 + l).
// ---------------------------------------------------------------------------
__global__ __launch_bounds__(512) void decoder_kernel(
    const float* __restrict__ enc, const float* __restrict__ mt,
    const float* __restrict__ dec_w, const float* __restrict__ dec_b,
    const float* __restrict__ fc1_w, const float* __restrict__ fc1_g,
    const float* __restrict__ fc1_b, const float* __restrict__ fc2_w,
    const float* __restrict__ fc2_g, const float* __restrict__ fc2_b,
    float* __restrict__ xnp_out, float* __restrict__ y2_out)
{
    __shared__ float mts[C_];
    __shared__ float qv[C_];
    __shared__ float aw[HEAD_ * L_];
    __shared__ float xnp[C_];
    __shared__ float y1[C_];
    const int t = threadIdx.x;
    const int b = blockIdx.x;
    const float* encb = enc + (size_t)b * C_ * L_;

    if (t < C_) mts[t] = mt[t];
    __syncthreads();

    // qv[o] = dec_b[o] + dec_w[o,:] . mt  (float4 dot)
    if (t < C_) {
        const float* wrow = dec_w + (size_t)t * C_;
        float s = 0.f;
        #pragma unroll 8
        for (int c4 = 0; c4 < C_; c4 += 4) {
            float4 w4 = *reinterpret_cast<const float4*>(&wrow[c4]);
            float4 m4 = *reinterpret_cast<const float4*>(&mts[c4]);
            s += w4.x * m4.x + w4.y * m4.y + w4.z * m4.z + w4.w * m4.w;
        }
        qv[t] = s + dec_b[t];
    }
    __syncthreads();

    // scores + softmax: t = h*64 + l, wave == head
    {
        int h = t >> 6, l = t & 63;
        float s = 0.f;
        #pragma unroll
        for (int cc = 0; cc < HC_; ++cc)
            s += qv[h * HC_ + cc] * encb[(h * HC_ + cc) * L_ + l];
        s *= SQRT32F;
        float m = s;
        #pragma unroll
        for (int off = 32; off >= 1; off >>= 1) m = fmaxf(m, __shfl_xor(m, off));
        float e = __expf(s - m);
        float sum = e;
        #pragma unroll
        for (int off = 32; off >= 1; off >>= 1) sum += __shfl_xor(sum, off);
        aw[t] = e / sum;
    }
    __syncthreads();

    // PV + residual: t<256 -> (h, cc)
    if (t < C_) {
        int h = t >> 5;
        const float* vrow = encb + t * L_;       // (h*32+cc)*64
        const float* awh  = aw + h * L_;
        float a = 0.f;
        #pragma unroll
        for (int k4 = 0; k4 < L_; k4 += 4) {
            float4 a4 = *reinterpret_cast<const float4*>(&awh[k4]);
            float4 v4 = *reinterpret_cast<const float4*>(&vrow[k4]);
            a += a4.x * v4.x + a4.y * v4.y + a4.z * v4.z + a4.w * v4.w;
        }
        float x = a + mts[t];
        xnp[t] = x;
        xnp_out[b * C_ + t] = x;
    }
    __syncthreads();

    // fc1 + BN(eval) + LeakyReLU(0.2)
    if (t < C_) {
        const float* wrow = fc1_w + (size_t)t * C_;
        float s = 0.f;
        #pragma unroll 8
        for (int c4 = 0; c4 < C_; c4 += 4) {
            float4 w4 = *reinterpret_cast<const float4*>(&wrow[c4]);
            float4 x4 = *reinterpret_cast<const float4*>(&xnp[c4]);
            s += w4.x * x4.x + w4.y * x4.y + w4.z * x4.z + w4.w * x4.w;
        }
        float y = fc1_g[t] * s * BN_INV + fc1_b[t];
        y1[t] = (y >= 0.f) ? y : 0.2f * y;
    }
    __syncthreads();

    if (t < 3) {
        float s = 0.f;
        for (int c = 0; c < C_; ++c) s += fc2_w[t * C_ + c] * y1[c];
        float y = fc2_g[t] * s * BN_INV + fc2_b[t];
        y2_out[b * 3 + t] = (y >= 0.f) ? y : 0.2f * y;
    }
}

// ---------------------------------------------------------------------------
// Kernel D: broadcast outputs (f32).
//   blocks 0..4095:   out0[b,c,:] = xnp[b,c]  (8192 f32 per block)
//   blocks 4096..4111: out1[b,:,:] = y2[b,:] tiled (8192x3, float4 patterns)
// ---------------------------------------------------------------------------
__global__ __launch_bounds__(256) void bcast_out(const float* __restrict__ xnp,
                                                 const float* __restrict__ y2,
                                                 float* __restrict__ out) {
    const int t = threadIdx.x;
    const int blk = blockIdx.x;
    if (blk < 4096) {
        float v = xnp[blk];
        float4 V = make_float4(v, v, v, v);
        float4* row = reinterpret_cast<float4*>(out + (size_t)blk * N_);
        #pragma unroll
        for (int i = 0; i < 8; ++i) row[t + i * 256] = V;   // 2048 x 16B
    } else {
        int b = blk - 4096;
        float v0 = y2[b * 3 + 0];
        float v1 = y2[b * 3 + 1];
        float v2 = y2[b * 3 + 2];
        float4 pat[3] = { make_float4(v0, v1, v2, v0),
                          make_float4(v1, v2, v0, v1),
                          make_float4(v2, v0, v1, v2) };
        float4* o1 = reinterpret_cast<float4*>(
            out + (size_t)B_ * C_ * N_ + (size_t)b * (N_ * 3));
        #pragma unroll
        for (int i = 0; i < 24; ++i) {       // 6144 float4 = 8192*3 f32
            int f = t + i * 256;
            o1[f] = pat[f % 3];
        }
    }
}

// ---------------------------------------------------------------------------
extern "C" void kernel_launch(void* const* d_in, const int* in_sizes, int n_in,
                              void* d_out, int out_size, void* d_ws, size_t ws_size,
                              hipStream_t stream) {
    const float* xt      = (const float*)d_in[0];
    // d_in[1] = xn : unused (length N is compile-time)
    const float* weights = (const float*)d_in[2];
    const float* mt      = (const float*)d_in[3];
    const float* enc_w   = (const float*)d_in[4];
    const float* enc_b   = (const float*)d_in[5];
    const float* dec_w   = (const float*)d_in[6];
    const float* dec_b   = (const float*)d_in[7];
    const float* fc1_w   = (const float*)d_in[8];
    const float* fc1_g   = (const float*)d_in[9];
    const float* fc1_b   = (const float*)d_in[10];
    const float* fc2_w   = (const float*)d_in[11];
    const float* fc2_g   = (const float*)d_in[12];
    const float* fc2_b   = (const float*)d_in[13];

    float* ws  = (float*)d_ws;
    float* Y   = ws;                  // 768*1024 = 786432 floats (3 MB)
    float* enc = ws + 786432;         // 262144 floats (1 MB)
    float* xnp = ws + 1048576;        // 4096 floats
    float* y2  = ws + 1052672;        // 48 floats

    float* out = (float*)d_out;

    qkv_gemm<<<dim3(16, 12), 128, 0, stream>>>(enc_w, enc_b, xt, Y);
    enc_attn<<<256, 256, 0, stream>>>(Y, xt, weights, enc);
    decoder_kernel<<<16, 512, 0, stream>>>(enc, mt, dec_w, dec_b,
                                           fc1_w, fc1_g, fc1_b,
                                           fc2_w, fc2_g, fc2_b, xnp, y2);
    bcast_out<<<4112, 256, 0, stream>>>(xnp, y2, out);
}

// Round 7
// 68.927 us; speedup vs baseline: 3.2375x; 1.2075x over previous
//
#include <hip/hip_runtime.h>
#include <hip/hip_bf16.h>
#include <math.h>

// Problem constants
#define B_    16
#define C_    256
#define L_    64
#define N_    8192
#define HEAD_ 8
#define HC_   32        // C/HEAD
#define M_    12
#define BL_   1024      // B*L

#define SQRT32F 5.656854249492380f
#define PI_F    3.14159265358979323846f
#define BN_INV  0.99999500003749969f     // 1/sqrt(1+1e-5)

// ---------------------------------------------------------------------------
// Kernel A: qkv = enc_w (768x256) @ X (256x1024) + enc_b
// Grid (16, 25): y<24 -> 32x64 GEMM tiles (384 blocks, 2x per-thread FMA cut);
//                y==24,x==0 -> qv = dec_w @ mask_token + dec_b (off critical path)
// ---------------------------------------------------------------------------
__global__ __launch_bounds__(128) void qkv_gemm(const float* __restrict__ enc_w,
                                                const float* __restrict__ enc_b,
                                                const float* __restrict__ xt,
                                                const float* __restrict__ dec_w,
                                                const float* __restrict__ dec_b,
                                                const float* __restrict__ mt,
                                                float* __restrict__ Y,
                                                float* __restrict__ qv_out) {
    __shared__ float As_t[32][36];   // [kk][r] transposed A, pad 36
    __shared__ float Bs[32][64];
    const int t = threadIdx.x;       // 0..127

    if (blockIdx.y == 24) {
        // qv block: 256 rows, 2 per thread
        if (blockIdx.x != 0) return;
        __shared__ float mts[C_];
        mts[t] = mt[t];
        mts[t + 128] = mt[t + 128];
        __syncthreads();
        #pragma unroll
        for (int rr = 0; rr < 2; ++rr) {
            int r = t + rr * 128;
            const float* wrow = dec_w + (size_t)r * C_;
            float s = 0.f;
            #pragma unroll 8
            for (int c4 = 0; c4 < C_; c4 += 4) {
                float4 w4 = *reinterpret_cast<const float4*>(&wrow[c4]);
                float4 m4 = *reinterpret_cast<const float4*>(&mts[c4]);
                s += w4.x * m4.x + w4.y * m4.y + w4.z * m4.z + w4.w * m4.w;
            }
            qv_out[r] = s + dec_b[r];
        }
        return;
    }

    const int b  = blockIdx.x;           // 0..15 (col tile)
    const int o0 = blockIdx.y * 32;      // 0..736 (row tile)
    const float* xb = xt + (size_t)b * (C_ * L_);
    const int tx = t & 15;               // cols tx*4
    const int ty = t >> 4;               // rows ty*4 (0..7)
    float4 acc[4] = {};                  // [row i][col quad]

    for (int k0 = 0; k0 < 256; k0 += 32) {
        // A tile: 32 rows x 32 k, float4 along k, store transposed
        #pragma unroll
        for (int i = 0; i < 2; ++i) {
            int q = t + i * 128;             // 0..255 quads
            int kk4 = (q & 7) * 4, r = q >> 3;
            float4 w4 = *reinterpret_cast<const float4*>(
                &enc_w[(size_t)(o0 + r) * 256 + k0 + kk4]);
            As_t[kk4 + 0][r] = w4.x;
            As_t[kk4 + 1][r] = w4.y;
            As_t[kk4 + 2][r] = w4.z;
            As_t[kk4 + 3][r] = w4.w;
        }
        // B tile: 32 k x 64 cols
        #pragma unroll
        for (int i = 0; i < 4; ++i) {
            int q = t + i * 128;             // 0..511 quads
            int jj4 = (q & 15) * 4, kk = q >> 4;
            *reinterpret_cast<float4*>(&Bs[kk][jj4]) =
                *reinterpret_cast<const float4*>(&xb[(k0 + kk) * 64 + jj4]);
        }
        __syncthreads();
        #pragma unroll
        for (int kk = 0; kk < 32; ++kk) {
            float4 a4 = *reinterpret_cast<const float4*>(&As_t[kk][ty * 4]);
            float4 b4 = *reinterpret_cast<const float4*>(&Bs[kk][tx * 4]);
            float as[4] = {a4.x, a4.y, a4.z, a4.w};
            #pragma unroll
            for (int ii = 0; ii < 4; ++ii) {
                acc[ii].x += as[ii] * b4.x; acc[ii].y += as[ii] * b4.y;
                acc[ii].z += as[ii] * b4.z; acc[ii].w += as[ii] * b4.w;
            }
        }
        __syncthreads();
    }
    #pragma unroll
    for (int ii = 0; ii < 4; ++ii) {
        int o = o0 + ty * 4 + ii;
        float bias = enc_b[o];
        float4 w = acc[ii];
        w.x += bias; w.y += bias; w.z += bias; w.w += bias;
        *reinterpret_cast<float4*>(&Y[(size_t)o * BL_ + b * 64 + tx * 4]) = w;
    }
}

// ---------------------------------------------------------------------------
// Kernel B: per (b,h,half) encoder attention + Fourier + residual.
// 256 blocks; each handles 32 query rows. (unchanged from round 6)
// ---------------------------------------------------------------------------
__global__ __launch_bounds__(256) void enc_attn(const float* __restrict__ Y,
                                                const float* __restrict__ xt,
                                                const float* __restrict__ weights,
                                                float* __restrict__ enc) {
    __shared__ float qs[HC_][33];
    __shared__ float ks[HC_][68];
    __shared__ float vs[HC_][68];
    __shared__ float P[32][68];
    const int t    = threadIdx.x;
    const int bh   = blockIdx.x >> 1;
    const int half = blockIdx.x & 1;
    const int b    = bh >> 3;
    const int h    = bh & 7;
    const float* xtb = xt + (size_t)b * (C_ * L_);

    for (int idx = t; idx < HC_ * L_; idx += 256) {
        int cc = idx >> 6, l = idx & 63;
        int col = b * 64 + l;
        ks[cc][l] = Y[(size_t)(256 + h * HC_ + cc) * BL_ + col];
        vs[cc][l] = Y[(size_t)(512 + h * HC_ + cc) * BL_ + col];
    }
    for (int idx = t; idx < HC_ * 32; idx += 256) {
        int cc = idx >> 5, l = idx & 31;
        qs[cc][l] = Y[(size_t)(h * HC_ + cc) * BL_ + b * 64 + half * 32 + l];
    }
    __syncthreads();

    #pragma unroll
    for (int i = 0; i < 2; ++i) {
        int e4 = t + i * 256;
        int l  = e4 >> 4;
        int lq = (e4 & 15) * 4;
        float4 a4 = make_float4(0.f, 0.f, 0.f, 0.f);
        #pragma unroll
        for (int cc = 0; cc < HC_; ++cc) {
            float4 k4 = *reinterpret_cast<const float4*>(&ks[cc][lq]);
            float qv_ = qs[cc][l];
            a4.x += qv_ * k4.x; a4.y += qv_ * k4.y;
            a4.z += qv_ * k4.z; a4.w += qv_ * k4.w;
        }
        a4.x *= SQRT32F; a4.y *= SQRT32F; a4.z *= SQRT32F; a4.w *= SQRT32F;
        *reinterpret_cast<float4*>(&P[l][lq]) = a4;
    }
    __syncthreads();

    if (t < 128) {
        int l = t >> 2, p0 = (t & 3) * 16;
        float m = -1e30f;
        #pragma unroll
        for (int j = 0; j < 16; ++j) m = fmaxf(m, P[l][p0 + j]);
        m = fmaxf(m, __shfl_xor(m, 1));
        m = fmaxf(m, __shfl_xor(m, 2));
        float sum = 0.f;
        #pragma unroll
        for (int j = 0; j < 16; ++j) {
            float e = __expf(P[l][p0 + j] - m);
            P[l][p0 + j] = e;
            sum += e;
        }
        sum += __shfl_xor(sum, 1);
        sum += __shfl_xor(sum, 2);
        float inv = 1.0f / sum;
        #pragma unroll
        for (int j = 0; j < 16; ++j) P[l][p0 + j] *= inv;
    }
    __syncthreads();

    #pragma unroll
    for (int i = 0; i < 4; ++i) {
        int e  = t + i * 256;
        int l  = e & 31;
        int cc = e >> 5;
        float a = 0.f;
        #pragma unroll
        for (int sq = 0; sq < 16; ++sq) {
            float4 p4 = *reinterpret_cast<const float4*>(&P[l][sq * 4]);
            float4 v4 = *reinterpret_cast<const float4*>(&vs[cc][sq * 4]);
            a += p4.x * v4.x + p4.y * v4.y + p4.z * v4.z + p4.w * v4.w;
        }
        int c  = h * HC_ + cc;
        int lg = half * 32 + l;
        float val = xtb[c * L_ + lg];
        const float* wr = weights + c * (2 * M_);
        float base = a * (PI_F / (float)M_);
        #pragma unroll
        for (int m = 0; m < M_; ++m) {
            float sn, cs;
            __sincosf((float)m * base, &sn, &cs);
            val += wr[m] * sn + wr[M_ + m] * cs;
        }
        enc[((size_t)b * C_ + c) * L_ + lg] = val;
    }
}

// ---------------------------------------------------------------------------
// Kernel C: decoder attention only. 128 blocks (b,h) x 64 lanes.
// Query qv precomputed; scores + wave softmax + PV -> xnp.
// ---------------------------------------------------------------------------
__global__ __launch_bounds__(64) void dec_attn(const float* __restrict__ enc,
                                               const float* __restrict__ qv,
                                               const float* __restrict__ mt,
                                               float* __restrict__ xnp_out) {
    __shared__ float aw[L_];
    const int l = threadIdx.x;           // 0..63
    const int b = blockIdx.x >> 3;
    const int h = blockIdx.x & 7;
    const float* ench = enc + ((size_t)b * C_ + h * HC_) * L_;

    float s = 0.f;
    #pragma unroll
    for (int cc = 0; cc < HC_; ++cc)
        s += qv[h * HC_ + cc] * ench[cc * L_ + l];   // coalesced over l
    s *= SQRT32F;
    float m = s;
    #pragma unroll
    for (int off = 32; off >= 1; off >>= 1) m = fmaxf(m, __shfl_xor(m, off));
    float e = __expf(s - m);
    float sum = e;
    #pragma unroll
    for (int off = 32; off >= 1; off >>= 1) sum += __shfl_xor(sum, off);
    aw[l] = e / sum;
    __syncthreads();

    if (l < HC_) {
        const float* vrow = ench + l * L_;
        float a = 0.f;
        #pragma unroll
        for (int k4 = 0; k4 < L_; k4 += 4) {
            float4 a4 = *reinterpret_cast<const float4*>(&aw[k4]);
            float4 v4 = *reinterpret_cast<const float4*>(&vrow[k4]);
            a += a4.x * v4.x + a4.y * v4.y + a4.z * v4.z + a4.w * v4.w;
        }
        int c = h * HC_ + l;
        xnp_out[b * C_ + c] = a + mt[c];
    }
}

// ---------------------------------------------------------------------------
// Kernel D: broadcast out0 + (fc1/fc2 + broadcast) out1.
//   blocks 0..4095:    out0[b,c,:] = xnp[b,c]
//   blocks 4096..4111: compute y2[b,:] from xnp[b,:] then tile 8192x3
// ---------------------------------------------------------------------------
__global__ __launch_bounds__(256) void bcast_fc(const float* __restrict__ xnp,
                                                const float* __restrict__ fc1_w,
                                                const float* __restrict__ fc1_g,
                                                const float* __restrict__ fc1_b,
                                                const float* __restrict__ fc2_w,
                                                const float* __restrict__ fc2_g,
                                                const float* __restrict__ fc2_b,
                                                float* __restrict__ out) {
    const int t = threadIdx.x;
    const int blk = blockIdx.x;
    if (blk < 4096) {
        float v = xnp[blk];
        float4 V = make_float4(v, v, v, v);
        float4* row = reinterpret_cast<float4*>(out + (size_t)blk * N_);
        #pragma unroll
        for (int i = 0; i < 8; ++i) row[t + i * 256] = V;   // 2048 x 16B
    } else {
        int b = blk - 4096;
        __shared__ float xs[C_];
        __shared__ float y1[C_];
        __shared__ float y2s[4];
        xs[t] = xnp[b * C_ + t];
        __syncthreads();
        // fc1 + BN + LeakyReLU
        {
            const float* wrow = fc1_w + (size_t)t * C_;
            float s = 0.f;
            #pragma unroll 8
            for (int c4 = 0; c4 < C_; c4 += 4) {
                float4 w4 = *reinterpret_cast<const float4*>(&wrow[c4]);
                float4 x4 = *reinterpret_cast<const float4*>(&xs[c4]);
                s += w4.x * x4.x + w4.y * x4.y + w4.z * x4.z + w4.w * x4.w;
            }
            float y = fc1_g[t] * s * BN_INV + fc1_b[t];
            y1[t] = (y >= 0.f) ? y : 0.2f * y;
        }
        __syncthreads();
        if (t < 3) {
            const float* wrow = fc2_w + t * C_;
            float s = 0.f;
            #pragma unroll 8
            for (int c4 = 0; c4 < C_; c4 += 4) {
                float4 w4 = *reinterpret_cast<const float4*>(&wrow[c4]);
                float4 x4 = *reinterpret_cast<const float4*>(&y1[c4]);
                s += w4.x * x4.x + w4.y * x4.y + w4.z * x4.z + w4.w * x4.w;
            }
            float y = fc2_g[t] * s * BN_INV + fc2_b[t];
            y2s[t] = (y >= 0.f) ? y : 0.2f * y;
        }
        __syncthreads();
        float v0 = y2s[0], v1 = y2s[1], v2 = y2s[2];
        float4 pat[3] = { make_float4(v0, v1, v2, v0),
                          make_float4(v1, v2, v0, v1),
                          make_float4(v2, v0, v1, v2) };
        float4* o1 = reinterpret_cast<float4*>(
            out + (size_t)B_ * C_ * N_ + (size_t)b * (N_ * 3));
        #pragma unroll
        for (int i = 0; i < 24; ++i) {       // 6144 float4 = 8192*3 f32
            int f = t + i * 256;
            o1[f] = pat[f % 3];
        }
    }
}

// ---------------------------------------------------------------------------
extern "C" void kernel_launch(void* const* d_in, const int* in_sizes, int n_in,
                              void* d_out, int out_size, void* d_ws, size_t ws_size,
                              hipStream_t stream) {
    const float* xt      = (const float*)d_in[0];
    // d_in[1] = xn : unused (length N is compile-time)
    const float* weights = (const float*)d_in[2];
    const float* mt      = (const float*)d_in[3];
    const float* enc_w   = (const float*)d_in[4];
    const float* enc_b   = (const float*)d_in[5];
    const float* dec_w   = (const float*)d_in[6];
    const float* dec_b   = (const float*)d_in[7];
    const float* fc1_w   = (const float*)d_in[8];
    const float* fc1_g   = (const float*)d_in[9];
    const float* fc1_b   = (const float*)d_in[10];
    const float* fc2_w   = (const float*)d_in[11];
    const float* fc2_g   = (const float*)d_in[12];
    const float* fc2_b   = (const float*)d_in[13];

    float* ws  = (float*)d_ws;
    float* Y   = ws;                  // 786432 floats (3 MB)
    float* enc = ws + 786432;         // 262144 floats (1 MB)
    float* xnp = ws + 1048576;        // 4096 floats
    float* qv  = ws + 1052672;        // 256 floats

    float* out = (float*)d_out;

    qkv_gemm<<<dim3(16, 25), 128, 0, stream>>>(enc_w, enc_b, xt,
                                               dec_w, dec_b, mt, Y, qv);
    enc_attn<<<256, 256, 0, stream>>>(Y, xt, weights, enc);
    dec_attn<<<128, 64, 0, stream>>>(enc, qv, mt, xnp);
    bcast_fc<<<4112, 256, 0, stream>>>(xnp, fc1_w, fc1_g, fc1_b,
                                       fc2_w, fc2_g, fc2_b, out);
}

// Round 8
// 67.610 us; speedup vs baseline: 3.3005x; 1.0195x over previous
//
#include <hip/hip_runtime.h>
#include <hip/hip_bf16.h>
#include <math.h>

// Problem constants
#define B_    16
#define C_    256
#define L_    64
#define N_    8192
#define HEAD_ 8
#define HC_   32        // C/HEAD
#define M_    12

#define SQRT32F 5.656854249492380f
#define PI_F    3.14159265358979323846f
#define BN_INV  0.99999500003749969f     // 1/sqrt(1+1e-5)

// ---------------------------------------------------------------------------
// Kernel 1: fully fused encoder+decoder per (b,h). 128 blocks x 512 threads.
//   phase 1: stage xt[b] (256x64 = 64 KB) -> LDS
//   phase 2: qkv GEMM (96 rows x 64 cols, K=256) from LDS-X / global-W
//            + qv = dec_w[h-slice] @ mt + dec_b (128 threads, shfl-reduce)
//   phase 3: scores 64x64, softmax (4 thr/row), PV + Fourier + residual
//            -> enc tile stays in LDS
//   phase 4: decoder attention (constant query) -> xnp[b, h-slice]
// No Y / enc global round-trips; 2 kernels total in the pipeline.
// ---------------------------------------------------------------------------
__global__ __launch_bounds__(512) void fused_enc(
    const float* __restrict__ xt, const float* __restrict__ enc_w,
    const float* __restrict__ enc_b, const float* __restrict__ weights,
    const float* __restrict__ dec_w, const float* __restrict__ dec_b,
    const float* __restrict__ mt, float* __restrict__ xnp_out)
{
    __shared__ float Xs[C_][L_];          // 64 KB  xt[b] as [c][l]
    __shared__ float qkv_s[96][68];       // 25.5 KB  rows: 0..31 q, 32..63 k, 64..95 v
    __shared__ float P[L_][68];           // 17 KB
    __shared__ float enc_t[HC_][68];      // 8.5 KB
    __shared__ float qvs[HC_];
    __shared__ float aw[L_];
    const int t = threadIdx.x;            // 0..511
    const int b = blockIdx.x >> 3;
    const int h = blockIdx.x & 7;
    const float* xtb = xt + (size_t)b * (C_ * L_);

    // ---- phase 1: stage xt[b] (coalesced float4) ----
    #pragma unroll
    for (int i = 0; i < 8; ++i) {
        int q = t + i * 512;              // 0..4095 quads
        int c = q >> 4, l4 = (q & 15) * 4;
        *reinterpret_cast<float4*>(&Xs[c][l4]) =
            *reinterpret_cast<const float4*>(&xtb[q * 4]);
    }
    __syncthreads();

    // ---- phase 2: qkv GEMM. thread (ty,tx): rows ty*3..+2, cols tx*4..+3 ----
    {
        const int tx = t & 15, ty = t >> 4;    // ty 0..31
        float acc[3][4] = {};
        int og[3];
        const float* wrow[3];
        #pragma unroll
        for (int r = 0; r < 3; ++r) {
            int o_loc = ty * 3 + r;            // 0..95
            int sec = o_loc >> 5, cc = o_loc & 31;
            og[r] = sec * C_ + h * HC_ + cc;
            wrow[r] = enc_w + (size_t)og[r] * C_;
        }
        #pragma unroll 2
        for (int c0 = 0; c0 < C_; c0 += 4) {
            float4 x0 = *reinterpret_cast<const float4*>(&Xs[c0 + 0][tx * 4]);
            float4 x1 = *reinterpret_cast<const float4*>(&Xs[c0 + 1][tx * 4]);
            float4 x2 = *reinterpret_cast<const float4*>(&Xs[c0 + 2][tx * 4]);
            float4 x3 = *reinterpret_cast<const float4*>(&Xs[c0 + 3][tx * 4]);
            #pragma unroll
            for (int r = 0; r < 3; ++r) {
                float4 w4 = *reinterpret_cast<const float4*>(&wrow[r][c0]);
                acc[r][0] += w4.x * x0.x + w4.y * x1.x + w4.z * x2.x + w4.w * x3.x;
                acc[r][1] += w4.x * x0.y + w4.y * x1.y + w4.z * x2.y + w4.w * x3.y;
                acc[r][2] += w4.x * x0.z + w4.y * x1.z + w4.z * x2.z + w4.w * x3.z;
                acc[r][3] += w4.x * x0.w + w4.y * x1.w + w4.z * x2.w + w4.w * x3.w;
            }
        }
        #pragma unroll
        for (int r = 0; r < 3; ++r) {
            float bias = enc_b[og[r]];
            float4 v = make_float4(acc[r][0] + bias, acc[r][1] + bias,
                                   acc[r][2] + bias, acc[r][3] + bias);
            *reinterpret_cast<float4*>(&qkv_s[ty * 3 + r][tx * 4]) = v;
        }
    }
    // qv: 32 rows x 4 partial-threads, shfl-xor combine
    if (t < 128) {
        int cc = t >> 2, part = t & 3;
        const float* wr = dec_w + (size_t)(h * HC_ + cc) * C_ + part * 64;
        const float* mp = mt + part * 64;
        float s = 0.f;
        #pragma unroll
        for (int j = 0; j < 16; ++j) {
            float4 w4 = *reinterpret_cast<const float4*>(&wr[j * 4]);
            float4 m4 = *reinterpret_cast<const float4*>(&mp[j * 4]);
            s += w4.x * m4.x + w4.y * m4.y + w4.z * m4.z + w4.w * m4.w;
        }
        s += __shfl_xor(s, 1);
        s += __shfl_xor(s, 2);
        if (part == 0) qvs[cc] = s + dec_b[h * HC_ + cc];
    }
    __syncthreads();

    // ---- phase 3a: scores P[l][lp] ----
    #pragma unroll
    for (int i = 0; i < 2; ++i) {
        int q = t + i * 512;              // 0..1023 quad-slots
        int l = q >> 4, lq = (q & 15) * 4;
        float4 a4 = make_float4(0.f, 0.f, 0.f, 0.f);
        #pragma unroll
        for (int cc = 0; cc < HC_; ++cc) {
            float qv_ = qkv_s[cc][l];
            float4 k4 = *reinterpret_cast<const float4*>(&qkv_s[32 + cc][lq]);
            a4.x += qv_ * k4.x; a4.y += qv_ * k4.y;
            a4.z += qv_ * k4.z; a4.w += qv_ * k4.w;
        }
        a4.x *= SQRT32F; a4.y *= SQRT32F; a4.z *= SQRT32F; a4.w *= SQRT32F;
        *reinterpret_cast<float4*>(&P[l][lq]) = a4;
    }
    __syncthreads();

    // ---- phase 3b: softmax, 4 threads/row ----
    if (t < 256) {
        int l = t >> 2, p0 = (t & 3) * 16;
        float m = -1e30f;
        #pragma unroll
        for (int j = 0; j < 16; ++j) m = fmaxf(m, P[l][p0 + j]);
        m = fmaxf(m, __shfl_xor(m, 1));
        m = fmaxf(m, __shfl_xor(m, 2));
        float sum = 0.f;
        #pragma unroll
        for (int j = 0; j < 16; ++j) {
            float e = __expf(P[l][p0 + j] - m);
            P[l][p0 + j] = e;
            sum += e;
        }
        sum += __shfl_xor(sum, 1);
        sum += __shfl_xor(sum, 2);
        float inv = 1.0f / sum;
        #pragma unroll
        for (int j = 0; j < 16; ++j) P[l][p0 + j] *= inv;
    }
    __syncthreads();

    // ---- phase 3c: PV + Fourier + residual -> enc_t (stays in LDS) ----
    #pragma unroll
    for (int i = 0; i < 4; ++i) {
        int e  = t + i * 512;             // 0..2047
        int cc = e >> 6, l = e & 63;
        float a = 0.f;
        #pragma unroll
        for (int sq = 0; sq < 16; ++sq) {
            float4 p4 = *reinterpret_cast<const float4*>(&P[l][sq * 4]);
            float4 v4 = *reinterpret_cast<const float4*>(&qkv_s[64 + cc][sq * 4]);
            a += p4.x * v4.x + p4.y * v4.y + p4.z * v4.z + p4.w * v4.w;
        }
        int c = h * HC_ + cc;
        float val = Xs[c][l];             // residual straight from LDS
        const float* wr = weights + c * (2 * M_);
        float base = a * (PI_F / (float)M_);
        #pragma unroll
        for (int m = 0; m < M_; ++m) {
            float sn, cs;
            __sincosf((float)m * base, &sn, &cs);
            val += wr[m] * sn + wr[M_ + m] * cs;
        }
        enc_t[cc][l] = val;
    }
    __syncthreads();

    // ---- phase 4: decoder attention (constant query) ----
    if (t < L_) {
        float s = 0.f;
        #pragma unroll
        for (int cc = 0; cc < HC_; ++cc) s += qvs[cc] * enc_t[cc][t];
        s *= SQRT32F;
        float m = s;
        #pragma unroll
        for (int off = 32; off >= 1; off >>= 1) m = fmaxf(m, __shfl_xor(m, off));
        float e = __expf(s - m);
        float sum = e;
        #pragma unroll
        for (int off = 32; off >= 1; off >>= 1) sum += __shfl_xor(sum, off);
        aw[t] = e / sum;
    }
    __syncthreads();
    if (t < HC_) {
        float a = 0.f;
        #pragma unroll
        for (int k4 = 0; k4 < L_; k4 += 4) {
            float4 a4 = *reinterpret_cast<const float4*>(&aw[k4]);
            float4 v4 = *reinterpret_cast<const float4*>(&enc_t[t][k4]);
            a += a4.x * v4.x + a4.y * v4.y + a4.z * v4.z + a4.w * v4.w;
        }
        int c = h * HC_ + t;
        xnp_out[b * C_ + c] = a + mt[c];
    }
}

// ---------------------------------------------------------------------------
// Kernel 2: broadcast out0 + (fc1/fc2 + broadcast) out1.  (proven)
// ---------------------------------------------------------------------------
__global__ __launch_bounds__(256) void bcast_fc(const float* __restrict__ xnp,
                                                const float* __restrict__ fc1_w,
                                                const float* __restrict__ fc1_g,
                                                const float* __restrict__ fc1_b,
                                                const float* __restrict__ fc2_w,
                                                const float* __restrict__ fc2_g,
                                                const float* __restrict__ fc2_b,
                                                float* __restrict__ out) {
    const int t = threadIdx.x;
    const int blk = blockIdx.x;
    if (blk < 4096) {
        float v = xnp[blk];
        float4 V = make_float4(v, v, v, v);
        float4* row = reinterpret_cast<float4*>(out + (size_t)blk * N_);
        #pragma unroll
        for (int i = 0; i < 8; ++i) row[t + i * 256] = V;   // 2048 x 16B
    } else {
        int b = blk - 4096;
        __shared__ float xs[C_];
        __shared__ float y1[C_];
        __shared__ float y2s[4];
        xs[t] = xnp[b * C_ + t];
        __syncthreads();
        {
            const float* wrow = fc1_w + (size_t)t * C_;
            float s = 0.f;
            #pragma unroll 8
            for (int c4 = 0; c4 < C_; c4 += 4) {
                float4 w4 = *reinterpret_cast<const float4*>(&wrow[c4]);
                float4 x4 = *reinterpret_cast<const float4*>(&xs[c4]);
                s += w4.x * x4.x + w4.y * x4.y + w4.z * x4.z + w4.w * x4.w;
            }
            float y = fc1_g[t] * s * BN_INV + fc1_b[t];
            y1[t] = (y >= 0.f) ? y : 0.2f * y;
        }
        __syncthreads();
        if (t < 3) {
            const float* wrow = fc2_w + t * C_;
            float s = 0.f;
            #pragma unroll 8
            for (int c4 = 0; c4 < C_; c4 += 4) {
                float4 w4 = *reinterpret_cast<const float4*>(&wrow[c4]);
                float4 x4 = *reinterpret_cast<const float4*>(&y1[c4]);
                s += w4.x * x4.x + w4.y * x4.y + w4.z * x4.z + w4.w * x4.w;
            }
            float y = fc2_g[t] * s * BN_INV + fc2_b[t];
            y2s[t] = (y >= 0.f) ? y : 0.2f * y;
        }
        __syncthreads();
        float v0 = y2s[0], v1 = y2s[1], v2 = y2s[2];
        float4 pat[3] = { make_float4(v0, v1, v2, v0),
                          make_float4(v1, v2, v0, v1),
                          make_float4(v2, v0, v1, v2) };
        float4* o1 = reinterpret_cast<float4*>(
            out + (size_t)B_ * C_ * N_ + (size_t)b * (N_ * 3));
        #pragma unroll
        for (int i = 0; i < 24; ++i) {       // 6144 float4 = 8192*3 f32
            int f = t + i * 256;
            o1[f] = pat[f % 3];
        }
    }
}

// ---------------------------------------------------------------------------
extern "C" void kernel_launch(void* const* d_in, const int* in_sizes, int n_in,
                              void* d_out, int out_size, void* d_ws, size_t ws_size,
                              hipStream_t stream) {
    const float* xt      = (const float*)d_in[0];
    // d_in[1] = xn : unused (length N is compile-time)
    const float* weights = (const float*)d_in[2];
    const float* mt      = (const float*)d_in[3];
    const float* enc_w   = (const float*)d_in[4];
    const float* enc_b   = (const float*)d_in[5];
    const float* dec_w   = (const float*)d_in[6];
    const float* dec_b   = (const float*)d_in[7];
    const float* fc1_w   = (const float*)d_in[8];
    const float* fc1_g   = (const float*)d_in[9];
    const float* fc1_b   = (const float*)d_in[10];
    const float* fc2_w   = (const float*)d_in[11];
    const float* fc2_g   = (const float*)d_in[12];
    const float* fc2_b   = (const float*)d_in[13];

    float* ws  = (float*)d_ws;
    float* xnp = ws;                  // 4096 floats

    float* out = (float*)d_out;

    fused_enc<<<128, 512, 0, stream>>>(xt, enc_w, enc_b, weights,
                                       dec_w, dec_b, mt, xnp);
    bcast_fc<<<4112, 256, 0, stream>>>(xnp, fc1_w, fc1_g, fc1_b,
                                       fc2_w, fc2_g, fc2_b, out);
}